// Round 3
// baseline (588.085 us; speedup 1.0000x reference)
//
#include <hip/hip_runtime.h>

typedef __bf16 bf16x8 __attribute__((ext_vector_type(8)));
typedef float  f32x4  __attribute__((ext_vector_type(4)));
typedef unsigned short u16;
typedef u16 u16x8 __attribute__((ext_vector_type(8)));

__device__ __forceinline__ u16 f2bf(float f) {
    unsigned u = __builtin_bit_cast(unsigned, f);
    return (u16)((u + 0x7FFFu + ((u >> 16) & 1u)) >> 16);  // RNE
}

__device__ __forceinline__ bf16x8 packA(f32x4 a0, f32x4 a1) {
    u16x8 h;
    h[0]=f2bf(a0[0]); h[1]=f2bf(a0[1]); h[2]=f2bf(a0[2]); h[3]=f2bf(a0[3]);
    h[4]=f2bf(a1[0]); h[5]=f2bf(a1[1]); h[6]=f2bf(a1[2]); h[7]=f2bf(a1[3]);
    return __builtin_bit_cast(bf16x8, h);
}

// ---------------------------------------------------------------------------
// Gather + transpose + fp32->bf16, coalesced both sides via LDS tile.
// Zero-pads k in [Kcnt, Kpad) so GEMM tail does garbage*0 = 0 safely.
// ---------------------------------------------------------------------------
__global__ __launch_bounds__(256) void gather_bt(
    const float* __restrict__ feats, const int* __restrict__ idx,
    u16* __restrict__ Bt, int Kcnt, int Kpad)
{
    __shared__ u16 st[128][66];
    const int tid = threadIdx.x;
    const int k0  = blockIdx.x * 64;

#pragma unroll
    for (int r2 = 0; r2 < 64; r2 += 2) {
        int r = r2 + (tid >> 7);
        int c = tid & 127;
        int k = k0 + r;
        float v = 0.f;
        if (k < Kcnt) v = feats[(size_t)idx[k] * 128 + c];
        st[c][r] = f2bf(v);
    }
    __syncthreads();

#pragma unroll
    for (int p = 0; p < 4; ++p) {
        int n  = p * 32 + (tid >> 3);
        int kk = (tid & 7) * 8;
        u16x8 v;
#pragma unroll
        for (int j = 0; j < 8; ++j) v[j] = st[n][kk + j];
        *(u16x8*)(Bt + (size_t)n * Kpad + k0 + kk) = v;
    }
}

// ---------------------------------------------------------------------------
// Split-K GEMM, macro-step structure: C[M][128] += A[M][K](f32) * Bt(bf16).
// Wave = 16 rows x 128 cols. Block = 4 waves = 64 rows.
// Macro-step = 256 k (8 MFMA k-steps). Per macro the wave issues ALL 16
// f32x4 A-loads back-to-back -> each A row is a 1KB sequential burst (DRAM
// row-buffer hits, 16KB in flight/wave) instead of isolated 128B touches.
// B fragments are register-prefetched one k-step ahead.
// grid = (ceil(M/64), ksplit); each split owns `mspan` macro-steps.
// fp32 atomicAdd epilogue (C pre-zeroed). Bt zero-padded to macro boundary.
// ---------------------------------------------------------------------------
__global__ __launch_bounds__(256, 2) void gemm_bt(
    const float* __restrict__ A, const u16* __restrict__ Bt,
    float* __restrict__ C, int M, int K, int Kpad, int mspan)
{
    const int wid  = threadIdx.x >> 6;
    const int lane = threadIdx.x & 63;
    const int l15  = lane & 15;
    const int lhi  = lane >> 4;

    const int row0 = blockIdx.x * 64 + wid * 16;
    const int macro_total = (K + 255) >> 8;
    int m0 = blockIdx.y * mspan;
    int m1 = m0 + mspan; if (m1 > macro_total) m1 = macro_total;
    if (m0 >= m1) return;

    f32x4 acc[8];
#pragma unroll
    for (int j = 0; j < 8; ++j) acc[j] = (f32x4){0.f, 0.f, 0.f, 0.f};

    const int rA = min(row0 + l15, M - 1);      // clamp; garbage rows discarded
    const float* __restrict__ ap  = A + (size_t)rA * K;
    const u16*   __restrict__ btl = Bt + (size_t)l15 * Kpad + lhi * 8;

    // prime B for the first k-step
    bf16x8 bcur[8];
    {
        const int kf = m0 << 8;
#pragma unroll
        for (int cf = 0; cf < 8; ++cf)
            bcur[cf] = __builtin_bit_cast(bf16x8,
                *(const u16x8*)(btl + (size_t)cf * 16 * Kpad + kf));
    }

    for (int m = m0; m < m1; ++m) {
        const int kbase = m << 8;

        // ---- A burst: 16 x f32x4, covers this macro's 256 k for this row ----
        f32x4 araw[16];
        if (kbase + 256 <= K) {
#pragma unroll
            for (int j = 0; j < 8; ++j) {
                const int koff = kbase + j * 32 + lhi * 8;
                araw[2 * j]     = *(const f32x4*)(ap + koff);
                araw[2 * j + 1] = *(const f32x4*)(ap + koff + 4);
            }
        } else {                                    // final macro only
#pragma unroll
            for (int j = 0; j < 8; ++j) {
                const int koff = kbase + j * 32 + lhi * 8;
                f32x4 a0, a1;
#pragma unroll
                for (int e = 0; e < 4; ++e) {
                    a0[e] = (koff + e     < K) ? ap[koff + e]     : 0.f;
                    a1[e] = (koff + 4 + e < K) ? ap[koff + 4 + e] : 0.f;
                }
                araw[2 * j] = a0; araw[2 * j + 1] = a1;
            }
        }

        // ---- 8 k-steps: B prefetched one step ahead ----
#pragma unroll
        for (int j = 0; j < 8; ++j) {
            const int knext = kbase + j * 32 + 32;   // Bt over-allocated: safe
            bf16x8 bnxt[8];
#pragma unroll
            for (int cf = 0; cf < 8; ++cf)
                bnxt[cf] = __builtin_bit_cast(bf16x8,
                    *(const u16x8*)(btl + (size_t)cf * 16 * Kpad + knext));

            const bf16x8 af = packA(araw[2 * j], araw[2 * j + 1]);
#pragma unroll
            for (int cf = 0; cf < 8; ++cf)
                acc[cf] = __builtin_amdgcn_mfma_f32_16x16x32_bf16(af, bcur[cf], acc[cf], 0, 0, 0);

#pragma unroll
            for (int cf = 0; cf < 8; ++cf) bcur[cf] = bnxt[cf];
        }
    }

    // C/D layout: col = lane&15, row = (lane>>4)*4 + i
#pragma unroll
    for (int cf = 0; cf < 8; ++cf)
#pragma unroll
        for (int i = 0; i < 4; ++i) {
            int r = row0 + lhi * 4 + i;
            if (r < M)
                atomicAdd(C + (size_t)r * 128 + cf * 16 + l15, acc[cf][i]);
        }
}

// ---------------------------------------------------------------------------
// out[M][128] = relu(concat(agg[M][128], fsrc[didx[m]][128]) @ w[256][128])
// ---------------------------------------------------------------------------
__global__ __launch_bounds__(256) void dense_relu(
    const float* __restrict__ agg, const float* __restrict__ fsrc,
    const int* __restrict__ didx, const float* __restrict__ w,
    float* __restrict__ out, int M)
{
    __shared__ float sb[32][257];
    const int tid  = threadIdx.x;
    const int row0 = blockIdx.x * 32;

    for (int i = tid; i < 32 * 32; i += 256) {           // agg half
        int r = i >> 5, c4 = (i & 31) << 2;
        int gr = row0 + r;
        f32x4 v = (f32x4){0.f, 0.f, 0.f, 0.f};
        if (gr < M) v = *(const f32x4*)(agg + (size_t)gr * 128 + c4);
        sb[r][c4 + 0] = v[0]; sb[r][c4 + 1] = v[1];
        sb[r][c4 + 2] = v[2]; sb[r][c4 + 3] = v[3];
    }
    for (int i = tid; i < 32 * 32; i += 256) {           // gathered dst half
        int r = i >> 5, c4 = (i & 31) << 2;
        int gr = row0 + r;
        int sr = (gr < M) ? didx[gr] : 0;
        f32x4 v = *(const f32x4*)(fsrc + (size_t)sr * 128 + c4);
        sb[r][128 + c4 + 0] = v[0]; sb[r][128 + c4 + 1] = v[1];
        sb[r][128 + c4 + 2] = v[2]; sb[r][128 + c4 + 3] = v[3];
    }
    __syncthreads();

    const int colg = (tid & 15) << 3;   // 8-col slab
    const int r0l  = (tid >> 4) * 2;    // 2 rows
    float acc0[8], acc1[8];
#pragma unroll
    for (int c = 0; c < 8; ++c) { acc0[c] = 0.f; acc1[c] = 0.f; }

#pragma unroll 4
    for (int j = 0; j < 256; ++j) {
        f32x4 wa = *(const f32x4*)(w + j * 128 + colg);
        f32x4 wb = *(const f32x4*)(w + j * 128 + colg + 4);
        float a0 = sb[r0l][j];
        float a1 = sb[r0l + 1][j];
#pragma unroll
        for (int c = 0; c < 4; ++c) {
            acc0[c]     += a0 * wa[c];  acc0[c + 4] += a0 * wb[c];
            acc1[c]     += a1 * wa[c];  acc1[c + 4] += a1 * wb[c];
        }
    }

    int gr0 = row0 + r0l;
    if (gr0 < M) {
#pragma unroll
        for (int c = 0; c < 8; ++c)
            out[(size_t)gr0 * 128 + colg + c] = fmaxf(acc0[c], 0.f);
    }
    int gr1 = gr0 + 1;
    if (gr1 < M) {
#pragma unroll
        for (int c = 0; c < 8; ++c)
            out[(size_t)gr1 * 128 + colg + c] = fmaxf(acc1[c], 0.f);
    }
}

// ---------------------------------------------------------------------------
extern "C" void kernel_launch(void* const* d_in, const int* in_sizes, int n_in,
                              void* d_out, int out_size, void* d_ws, size_t ws_size,
                              hipStream_t stream)
{
    const float* src_nodes = (const float*)d_in[0];
    const int*   s1idx     = (const int*)d_in[1];
    const int*   s2idx     = (const int*)d_in[2];
    const int*   d1idx     = (const int*)d_in[3];
    const int*   d2idx     = (const int*)d_in[4];
    const float* dif1      = (const float*)d_in[5];
    const float* dif2      = (const float*)d_in[6];
    const float* w1        = (const float*)d_in[7];
    const float* w2        = (const float*)d_in[8];
    float*       out       = (float*)d_out;

    const int S2 = 16000, M2 = 4000, S1 = 3500, M1 = 1024;
    const int K2 = 16000, K1 = 3500;
    const int Kpad2 = 16128;                 // 63 macro-steps * 256
    const int Kpad1 = 3584;                  // 14 macro-steps * 256

    char* ws = (char*)d_ws;
    size_t off = 0;
    float* agg2 = (float*)(ws + off); off += (size_t)M2 * 128 * 4;
    float* agg1 = (float*)(ws + off); off += (size_t)M1 * 128 * 4;
    float* x    = (float*)(ws + off); off += (size_t)M2 * 128 * 4;
    u16*   Bt2  = (u16*)(ws + off);   off += (size_t)128 * Kpad2 * 2 + 512; // slack for B overfetch
    u16*   Bt1  = (u16*)(ws + off);   off += (size_t)128 * Kpad1 * 2 + 512;

    // zero both atomic accumulators (contiguous)
    hipMemsetAsync(agg2, 0, (size_t)(M2 + M1) * 128 * 4, stream);

    // ---- hop 2 ----
    gather_bt<<<Kpad2 / 64, 256, 0, stream>>>(src_nodes, s2idx, Bt2, S2, Kpad2);

    {
        // 63 macros; ksplit=8 -> mspan=8; grid 63x8 = 504 blocks (~2/CU)
        dim3 grid((M2 + 63) / 64, 8);
        gemm_bt<<<grid, 256, 0, stream>>>(dif2, Bt2, agg2, M2, K2, Kpad2, 8);
    }

    dense_relu<<<(M2 + 31) / 32, 256, 0, stream>>>(agg2, src_nodes, d2idx, w1, x, M2);

    // ---- hop 1 ----
    gather_bt<<<Kpad1 / 64, 256, 0, stream>>>(x, s1idx, Bt1, S1, Kpad1);

    {
        // 14 macros; ksplit=14 -> mspan=1; grid 16x14 = 224 blocks
        dim3 grid((M1 + 63) / 64, 14);
        gemm_bt<<<grid, 256, 0, stream>>>(dif1, Bt1, agg1, M1, K1, Kpad1, 1);
    }

    dense_relu<<<(M1 + 31) / 32, 256, 0, stream>>>(agg1, x, d1idx, w2, out, M1);
}

// Round 4
// 521.983 us; speedup vs baseline: 1.1266x; 1.1266x over previous
//
#include <hip/hip_runtime.h>

typedef __bf16 bf16x8 __attribute__((ext_vector_type(8)));
typedef float  f32x4  __attribute__((ext_vector_type(4)));
typedef unsigned short u16;
typedef u16 u16x8 __attribute__((ext_vector_type(8)));

__device__ __forceinline__ bf16x8 packA(f32x4 a0, f32x4 a1) {
    bf16x8 r;
    r[0] = (__bf16)a0[0]; r[1] = (__bf16)a0[1]; r[2] = (__bf16)a0[2]; r[3] = (__bf16)a0[3];
    r[4] = (__bf16)a1[0]; r[5] = (__bf16)a1[1]; r[6] = (__bf16)a1[2]; r[7] = (__bf16)a1[3];
    return r;
}

// ---------------------------------------------------------------------------
// Gather + fp32->bf16 + FRAGMENT-PACK for the GEMM's B operand.
// Output layout: BP[((s*8 + cf)*64 + lane) * 8 + e]  (u16), where for kstep s
// fragment cf, lane = lhi*16 + l15 holds B[n = cf*16 + l15][k = s*32 + lhi*8 + e].
// A GEMM wave's B-load is then 64 lanes x 16B CONTIGUOUS (1KB).
// Block covers 64 k (2 ksteps) x 128 n. Zero-pads k >= Kcnt.
// ---------------------------------------------------------------------------
__global__ __launch_bounds__(256) void gather_bt(
    const float* __restrict__ feats, const int* __restrict__ idx,
    u16* __restrict__ BP, int Kcnt)
{
    __shared__ u16 st[128][72];          // st[n][k_local], stride 144B (16B-aligned, ~2-way banks)
    const int tid = threadIdx.x;
    const int k0  = blockIdx.x * 64;

#pragma unroll
    for (int r2 = 0; r2 < 64; r2 += 2) {
        int r = r2 + (tid >> 7);         // k_local
        int c = tid & 127;               // feature n
        int k = k0 + r;
        float v = 0.f;
        if (k < Kcnt) v = feats[(size_t)idx[k] * 128 + c];
        st[c][r] = __builtin_bit_cast(u16, (__bf16)v);
    }
    __syncthreads();

    const int s_local = tid >> 7;        // 0..1
    const int cf      = (tid >> 4) & 7;
    const int l15     = tid & 15;
    const int s       = blockIdx.x * 2 + s_local;
    const int n       = cf * 16 + l15;
#pragma unroll
    for (int lhi = 0; lhi < 4; ++lhi) {
        u16x8 v = *(const u16x8*)&st[n][s_local * 32 + lhi * 8];
        *(u16x8*)(BP + ((size_t)(s * 8 + cf) * 64 + lhi * 16 + l15) * 8) = v;
    }
}

// ---------------------------------------------------------------------------
// Split-K GEMM: C[M][128] += A[M][K](f32) * B (bf16, fragment-packed BP).
// Block = 4 waves = 64 rows; wave = 16 rows x 128 cols (16x16x32 MFMA).
// Macro = 128 k (4 ksteps). A staged global->LDS via global_load_lds (1KB
// fully-coalesced per instr), double-buffered; source-side XOR swizzle
// (unit ^= row&7) so fragment ds_read_b128s are bank-spread. B loads are 1KB
// contiguous register loads, pipelined one kstep ahead across barriers.
// One __syncthreads per macro (its vmcnt(0) drain covers the gload_lds).
// fp32 atomicAdd epilogue (C pre-zeroed). BP zero-padded past K.
// ---------------------------------------------------------------------------
__global__ __launch_bounds__(256, 2) void gemm_bt(
    const float* __restrict__ A, const u16* __restrict__ BP,
    float* __restrict__ C, int M, int K, int nmacro, int mspan, int nktot)
{
    __shared__ float As[2][64][128];     // 64KB, linear rows (512B stride)
    const int tid  = threadIdx.x;
    const int wid  = tid >> 6;
    const int lane = tid & 63;
    const int l15  = lane & 15;
    const int lhi  = lane >> 4;
    const int swz  = l15 & 7;
    const int row0 = blockIdx.x * 64 + wid * 16;

    int m0 = blockIdx.y * mspan;
    int m1 = m0 + mspan; if (m1 > nmacro) m1 = nmacro;
    if (m0 >= m1) return;                // uniform per block

    auto stage = [&](int m, int buf) {
        const int kbase = m << 7;
        if (kbase + 128 <= K) {          // fast path: async 1KB line-sequential
#pragma unroll
            for (int i = 0; i < 8; ++i) {
                const int lr = wid * 16 + i * 2 + (lane >> 5);       // local row
                const int ar = min(blockIdx.x * 64 + lr, M - 1);
                const float* src = A + (size_t)ar * K + kbase
                                 + (((lane & 31) ^ (lr & 7)) << 2);  // swizzled source
                __builtin_amdgcn_global_load_lds(
                    (const __attribute__((address_space(1))) void*)src,
                    (__attribute__((address_space(3))) void*)&As[buf][wid * 16 + i * 2][0],
                    16, 0, 0);
            }
        } else {                          // tail macro (hop-1 only): guarded reg-stage
#pragma unroll
            for (int i = 0; i < 8; ++i) {
                const int lr = wid * 16 + i * 2 + (lane >> 5);
                const int ar = min(blockIdx.x * 64 + lr, M - 1);
                const int u  = lane & 31;
                const float* src = A + (size_t)ar * K + kbase + (u << 2);
                f32x4 v;
#pragma unroll
                for (int e = 0; e < 4; ++e) {
                    int kk = kbase + (u << 2) + e;
                    v[e] = (kk < K) ? src[e] : 0.f;
                }
                *(f32x4*)&As[buf][lr][(u ^ (lr & 7)) << 2] = v;
            }
        }
    };

    stage(m0, 0);

    f32x4 acc[8];
#pragma unroll
    for (int j = 0; j < 8; ++j) acc[j] = (f32x4){0.f, 0.f, 0.f, 0.f};

    const u16* __restrict__ bp_lane = BP + (size_t)lane * 8;

    bf16x8 bcur[8];
    {
        const int s_first = m0 << 2;
#pragma unroll
        for (int cf = 0; cf < 8; ++cf)
            bcur[cf] = __builtin_bit_cast(bf16x8,
                *(const u16x8*)(bp_lane + ((size_t)(s_first * 8 + cf) << 9)));
    }

    __builtin_amdgcn_s_waitcnt(0x0F70);  // vmcnt(0): gload_lds landed
    __syncthreads();

    for (int m = m0; m < m1; ++m) {
        const int buf = (m - m0) & 1;
        if (m + 1 < m1) stage(m + 1, buf ^ 1);

#pragma unroll
        for (int j = 0; j < 4; ++j) {
            const int s  = (m << 2) + j;
            int sn = s + 1; if (sn > nktot - 1) sn = nktot - 1;   // clamp (values unused past end)
            bf16x8 bnxt[8];
#pragma unroll
            for (int cf = 0; cf < 8; ++cf)
                bnxt[cf] = __builtin_bit_cast(bf16x8,
                    *(const u16x8*)(bp_lane + ((size_t)(sn * 8 + cf) << 9)));

            const int ub = (j << 3) + (lhi << 1);                  // fp32 16B-unit
            const f32x4 a0 = *(const f32x4*)&As[buf][wid * 16 + l15][(ub ^ swz) << 2];
            const f32x4 a1 = *(const f32x4*)&As[buf][wid * 16 + l15][((ub + 1) ^ swz) << 2];
            const bf16x8 af = packA(a0, a1);

#pragma unroll
            for (int cf = 0; cf < 8; ++cf)
                acc[cf] = __builtin_amdgcn_mfma_f32_16x16x32_bf16(af, bcur[cf], acc[cf], 0, 0, 0);

#pragma unroll
            for (int cf = 0; cf < 8; ++cf) bcur[cf] = bnxt[cf];
        }

        __builtin_amdgcn_s_waitcnt(0x0F70);  // vmcnt(0): next-buf stage landed
        __syncthreads();                     // + all waves done reading cur buf
    }

    // C/D layout: col = lane&15, row = (lane>>4)*4 + i
#pragma unroll
    for (int cf = 0; cf < 8; ++cf)
#pragma unroll
        for (int i = 0; i < 4; ++i) {
            const int r = row0 + lhi * 4 + i;
            if (r < M)
                atomicAdd(C + (size_t)r * 128 + cf * 16 + l15, acc[cf][i]);
        }
}

// ---------------------------------------------------------------------------
// out[M][128] = relu(concat(agg[M][128], fsrc[didx[m]][128]) @ w[256][128])
// ---------------------------------------------------------------------------
__global__ __launch_bounds__(256) void dense_relu(
    const float* __restrict__ agg, const float* __restrict__ fsrc,
    const int* __restrict__ didx, const float* __restrict__ w,
    float* __restrict__ out, int M)
{
    __shared__ float sb[32][257];
    const int tid  = threadIdx.x;
    const int row0 = blockIdx.x * 32;

    for (int i = tid; i < 32 * 32; i += 256) {           // agg half
        int r = i >> 5, c4 = (i & 31) << 2;
        int gr = row0 + r;
        f32x4 v = (f32x4){0.f, 0.f, 0.f, 0.f};
        if (gr < M) v = *(const f32x4*)(agg + (size_t)gr * 128 + c4);
        sb[r][c4 + 0] = v[0]; sb[r][c4 + 1] = v[1];
        sb[r][c4 + 2] = v[2]; sb[r][c4 + 3] = v[3];
    }
    for (int i = tid; i < 32 * 32; i += 256) {           // gathered dst half
        int r = i >> 5, c4 = (i & 31) << 2;
        int gr = row0 + r;
        int sr = (gr < M) ? didx[gr] : 0;
        f32x4 v = *(const f32x4*)(fsrc + (size_t)sr * 128 + c4);
        sb[r][128 + c4 + 0] = v[0]; sb[r][128 + c4 + 1] = v[1];
        sb[r][128 + c4 + 2] = v[2]; sb[r][128 + c4 + 3] = v[3];
    }
    __syncthreads();

    const int colg = (tid & 15) << 3;
    const int r0l  = (tid >> 4) * 2;
    float acc0[8], acc1[8];
#pragma unroll
    for (int c = 0; c < 8; ++c) { acc0[c] = 0.f; acc1[c] = 0.f; }

#pragma unroll 4
    for (int j = 0; j < 256; ++j) {
        f32x4 wa = *(const f32x4*)(w + j * 128 + colg);
        f32x4 wb = *(const f32x4*)(w + j * 128 + colg + 4);
        float a0 = sb[r0l][j];
        float a1 = sb[r0l + 1][j];
#pragma unroll
        for (int c = 0; c < 4; ++c) {
            acc0[c]     += a0 * wa[c];  acc0[c + 4] += a0 * wb[c];
            acc1[c]     += a1 * wa[c];  acc1[c + 4] += a1 * wb[c];
        }
    }

    int gr0 = row0 + r0l;
    if (gr0 < M) {
#pragma unroll
        for (int c = 0; c < 8; ++c)
            out[(size_t)gr0 * 128 + colg + c] = fmaxf(acc0[c], 0.f);
    }
    int gr1 = gr0 + 1;
    if (gr1 < M) {
#pragma unroll
        for (int c = 0; c < 8; ++c)
            out[(size_t)gr1 * 128 + colg + c] = fmaxf(acc1[c], 0.f);
    }
}

// ---------------------------------------------------------------------------
extern "C" void kernel_launch(void* const* d_in, const int* in_sizes, int n_in,
                              void* d_out, int out_size, void* d_ws, size_t ws_size,
                              hipStream_t stream)
{
    const float* src_nodes = (const float*)d_in[0];
    const int*   s1idx     = (const int*)d_in[1];
    const int*   s2idx     = (const int*)d_in[2];
    const int*   d1idx     = (const int*)d_in[3];
    const int*   d2idx     = (const int*)d_in[4];
    const float* dif1      = (const float*)d_in[5];
    const float* dif2      = (const float*)d_in[6];
    const float* w1        = (const float*)d_in[7];
    const float* w2        = (const float*)d_in[8];
    float*       out       = (float*)d_out;

    const int M2 = 4000, M1 = 1024;
    const int K2 = 16000, K1 = 3500;
    // hop2: 16000 = 125 macros * 128 exactly (no tail); 500 ksteps
    // hop1: pad to 3584 = 28 macros; 112 ksteps (BP zero-padded; A tail guarded)
    const int NK2 = 500, NK1 = 112;

    char* ws = (char*)d_ws;
    size_t off = 0;
    float* agg2 = (float*)(ws + off); off += (size_t)M2 * 128 * 4;
    float* agg1 = (float*)(ws + off); off += (size_t)M1 * 128 * 4;
    float* x    = (float*)(ws + off); off += (size_t)M2 * 128 * 4;
    u16*   BP2  = (u16*)(ws + off);   off += (size_t)NK2 * 8 * 64 * 8 * 2;  // 4.096 MB
    u16*   BP1  = (u16*)(ws + off);   off += (size_t)NK1 * 8 * 64 * 8 * 2;  // 0.918 MB

    // zero both atomic accumulators (contiguous)
    hipMemsetAsync(agg2, 0, (size_t)(M2 + M1) * 128 * 4, stream);

    // ---- hop 2 ----
    gather_bt<<<NK2 / 2, 256, 0, stream>>>(src_nodes, s2idx, BP2, K2);
    {
        // 125 macros; ksplit=8, mspan=16 (last split 13); grid 63x8 = 504 blocks
        dim3 grid((M2 + 63) / 64, 8);
        gemm_bt<<<grid, 256, 0, stream>>>(dif2, BP2, agg2, M2, K2, 125, 16, NK2);
    }
    dense_relu<<<(M2 + 31) / 32, 256, 0, stream>>>(agg2, src_nodes, d2idx, w1, x, M2);

    // ---- hop 1 ----
    gather_bt<<<NK1 / 2, 256, 0, stream>>>(x, s1idx, BP1, K1);
    {
        // 28 macros; ksplit=14, mspan=2; grid 16x14 = 224 blocks
        dim3 grid((M1 + 63) / 64, 14);
        gemm_bt<<<grid, 256, 0, stream>>>(dif1, BP1, agg1, M1, K1, 28, 2, NK1);
    }
    dense_relu<<<(M1 + 31) / 32, 256, 0, stream>>>(agg1, x, d1idx, w2, out, M1);
}